// Round 5
// baseline (452.193 us; speedup 1.0000x reference)
//
#include <hip/hip_runtime.h>
#include <cstdint>
#include <cstddef>

// ---------------------------------------------------------------------------
// GCN encoder: z = GCN3( relu(GCN2( relu(GCN1( LN(x) )) )) )
// R5: aggregation sliced into 32-column feature slices with XCD-affine
//     blockIdx mapping (slice = blockIdx & (NS-1); round-robin blockIdx%8->XCD
//     keeps each XCD's random gathers inside a 3.2 MB L2-resident slice).
//     Two edges per wave (half-wave split) x4 unroll = 8 gathers in flight.
//     CSR bucket sort + bf16x3 MFMA GEMMs unchanged from R4.
// ---------------------------------------------------------------------------

typedef __attribute__((ext_vector_type(8))) __bf16 bf16x8;
typedef __attribute__((ext_vector_type(4))) float f32x4;
typedef _Float16 half_t;
typedef __attribute__((ext_vector_type(8))) _Float16 half8_t;

// ---------------- CSR build: bucket sort by dst ----------------
__global__ void zero_ctl(int* __restrict__ p, int n) {
  int i = blockIdx.x * 256 + threadIdx.x;
  if (i < n) p[i] = 0;
}

__global__ __launch_bounds__(256) void hist_bucket(const int* __restrict__ dst,
                                                   int* __restrict__ bcnt, int E, int NB) {
  __shared__ int h[256];
  int t = threadIdx.x;
  h[t] = 0;
  __syncthreads();
  for (int e = blockIdx.x * 256 + t; e < E; e += gridDim.x * 256)
    atomicAdd(&h[dst[e] >> 8], 1);
  __syncthreads();
  if (t < NB && h[t]) atomicAdd(&bcnt[t], h[t]);
}

__global__ __launch_bounds__(256) void scan_buckets(const int* __restrict__ bcnt,
                                                    int* __restrict__ bbase,
                                                    int* __restrict__ bcur, int NB, int E) {
  __shared__ int tmp[256];
  int t = threadIdx.x;
  int v = (t < NB) ? bcnt[t] : 0;
  tmp[t] = v;
  __syncthreads();
  for (int off = 1; off < 256; off <<= 1) {
    int x = (t >= off) ? tmp[t - off] : 0;
    __syncthreads();
    tmp[t] += x;
    __syncthreads();
  }
  int excl = tmp[t] - v;
  if (t < NB) { bbase[t] = excl; bcur[t] = excl; }
  if (t == 0) bbase[NB] = E;
}

#define CHUNK 4096
__global__ __launch_bounds__(256) void scatter_bins(const int* __restrict__ src,
                                                    const int* __restrict__ dst,
                                                    int* __restrict__ bcur,
                                                    int2* __restrict__ binned, int E) {
  __shared__ int2 recs[CHUNK];
  __shared__ int hist[256], lbase[256], resv[256], cur[256];
  int t = threadIdx.x;
  int e0 = blockIdx.x * CHUNK;
  if (e0 >= E) return;
  int len = min(CHUNK, E - e0);
  hist[t] = 0;
  cur[t] = 0;
  __syncthreads();
  for (int i = t; i < len; i += 256) atomicAdd(&hist[dst[e0 + i] >> 8], 1);
  __syncthreads();
  int v = hist[t];
  lbase[t] = v;
  __syncthreads();
  for (int off = 1; off < 256; off <<= 1) {
    int x = (t >= off) ? lbase[t - off] : 0;
    __syncthreads();
    lbase[t] += x;
    __syncthreads();
  }
  int myexcl = lbase[t] - v;
  if (v) resv[t] = atomicAdd(&bcur[t], v);
  __syncthreads();
  lbase[t] = myexcl;
  __syncthreads();
  for (int i = t; i < len; i += 256) {
    int d = dst[e0 + i], s = src[e0 + i];
    int b = d >> 8;
    int r = atomicAdd(&cur[b], 1);
    recs[lbase[b] + r] = make_int2(s, d);
  }
  __syncthreads();
  for (int i = t; i < len; i += 256) {
    int2 rc = recs[i];
    int b = rc.y >> 8;
    binned[resv[b] + (i - lbase[b])] = rc;
  }
}

#define MAXB 8192
__global__ __launch_bounds__(256) void sort_bucket(const int2* __restrict__ binned,
                                                   const int* __restrict__ bbase,
                                                   int* __restrict__ srcs,
                                                   int* __restrict__ offs,
                                                   float* __restrict__ dinv,
                                                   int N, int NB, int E) {
  __shared__ int2 recs[MAXB];
  __shared__ unsigned short rnk[MAXB];
  __shared__ int sstage[MAXB];
  __shared__ int hist[256], nbase[256];
  int b = blockIdx.x, t = threadIdx.x;
  int base = bbase[b], end = bbase[b + 1];
  int L = end - base;
  if (L > MAXB) L = MAXB;
  hist[t] = 0;
  __syncthreads();
  for (int i = t; i < L; i += 256) {
    int2 rc = binned[base + i];
    recs[i] = rc;
    int r = atomicAdd(&hist[rc.y & 255], 1);
    rnk[i] = (unsigned short)r;
  }
  __syncthreads();
  int v = hist[t];
  nbase[t] = v;
  __syncthreads();
  for (int off = 1; off < 256; off <<= 1) {
    int x = (t >= off) ? nbase[t - off] : 0;
    __syncthreads();
    nbase[t] += x;
    __syncthreads();
  }
  int excl = nbase[t] - v;
  __syncthreads();
  nbase[t] = excl;
  int node = (b << 8) + t;
  if (node < N) {
    offs[node] = base + excl;
    dinv[node] = rsqrtf(1.0f + (float)v);
  }
  if (b == NB - 1 && t == 0) offs[N] = E;
  __syncthreads();
  for (int i = t; i < L; i += 256) {
    int2 rc = recs[i];
    sstage[nbase[rc.y & 255] + rnk[i]] = rc.x;
  }
  __syncthreads();
  for (int i = t; i < L; i += 256) srcs[base + i] = sstage[i];
}

__global__ void fill_w(const int* __restrict__ srcs, const float* __restrict__ dinv,
                       int2* __restrict__ edges, int E) {
  int e = blockIdx.x * 256 + threadIdx.x;
  if (e < E) {
    int s = srcs[e];
    edges[e] = make_int2(s, __float_as_int(dinv[s]));
  }
}

// ---------------- LN stats ----------------
__global__ void ln_stats(const float* __restrict__ x, float* __restrict__ mu,
                         float* __restrict__ rs, int n) {
  int gid = blockIdx.x * blockDim.x + threadIdx.x;
  int wv = gid >> 6, lane = gid & 63;
  if (wv >= n) return;
  const float4* row = (const float4*)(x + (size_t)wv * 256);
  float4 v = row[lane];
  float s = v.x + v.y + v.z + v.w;
  float s2 = v.x * v.x + v.y * v.y + v.z * v.z + v.w * v.w;
  for (int off = 32; off > 0; off >>= 1) {
    s += __shfl_down(s, off);
    s2 += __shfl_down(s2, off);
  }
  if (lane == 0) {
    float m = s * (1.0f / 256.0f);
    float var = s2 * (1.0f / 256.0f) - m * m;
    mu[wv] = m;
    rs[wv] = rsqrtf(var + 1e-5f);
  }
}

// W[K][NOUT] fp32 -> Wt_hi/Wt_lo[NOUT][K] bf16 bit patterns (B-operand layout)
__global__ void wsplit(const float* __restrict__ W, unsigned short* __restrict__ Wt_hi,
                       unsigned short* __restrict__ Wt_lo, int K, int NOUT) {
  int idx = blockIdx.x * 256 + threadIdx.x;
  if (idx >= K * NOUT) return;
  int k = idx / NOUT, n = idx % NOUT;
  float v = W[idx];
  __bf16 h = (__bf16)v;
  __bf16 l = (__bf16)(v - (float)h);
  Wt_hi[(size_t)n * K + k] = __builtin_bit_cast(unsigned short, h);
  Wt_lo[(size_t)n * K + k] = __builtin_bit_cast(unsigned short, l);
}

// out16[nrows x NOUT] = A[nrows x K] * W[K x NOUT] via bf16x3 MFMA.
template <int K, int NOUT, bool LN, bool A_FP16>
__launch_bounds__(256)
__global__ void gemm_mfma(const void* __restrict__ Avoid,
                          const unsigned short* __restrict__ Wt_hi,
                          const unsigned short* __restrict__ Wt_lo,
                          const float* __restrict__ mu, const float* __restrict__ rs,
                          const float* __restrict__ gamma, const float* __restrict__ beta,
                          half_t* __restrict__ out, int nrows) {
  constexpr int BM = 64, BK = 32;
  constexpr int NT = NOUT / 16;
  __shared__ unsigned short As_hi[BM][BK];
  __shared__ unsigned short As_lo[BM][BK];
  __shared__ unsigned short Bs_hi[NOUT][BK];
  __shared__ unsigned short Bs_lo[NOUT][BK];

  const int tid = threadIdx.x;
  const int lane = tid & 63;
  const int w = tid >> 6;
  const int quad = lane >> 4;
  const int l16 = lane & 15;
  const int row0 = blockIdx.x * BM;

  f32x4 acc[NT];
#pragma unroll
  for (int t = 0; t < NT; ++t) acc[t] = (f32x4){0.f, 0.f, 0.f, 0.f};

  for (int k0 = 0; k0 < K; k0 += BK) {
    if (!A_FP16) {
      const float* A = (const float*)Avoid;
#pragma unroll
      for (int i = 0; i < 2; ++i) {
        int r = i * 32 + (tid >> 3);
        int c4 = (tid & 7) * 4;
        int grow = row0 + r;
        if (grow > nrows - 1) grow = nrows - 1;
        float4 v = *(const float4*)&A[(size_t)grow * K + k0 + c4];
        if (LN) {
          float m = mu[grow], s = rs[grow];
          float4 g = *(const float4*)&gamma[k0 + c4];
          float4 b = *(const float4*)&beta[k0 + c4];
          v.x = (v.x - m) * s * g.x + b.x;
          v.y = (v.y - m) * s * g.y + b.y;
          v.z = (v.z - m) * s * g.z + b.z;
          v.w = (v.w - m) * s * g.w + b.w;
        }
        float vv[4] = {v.x, v.y, v.z, v.w};
#pragma unroll
        for (int j = 0; j < 4; ++j) {
          __bf16 h = (__bf16)vv[j];
          __bf16 l = (__bf16)(vv[j] - (float)h);
          As_hi[r][c4 + j] = __builtin_bit_cast(unsigned short, h);
          As_lo[r][c4 + j] = __builtin_bit_cast(unsigned short, l);
        }
      }
    } else {
      const half_t* A = (const half_t*)Avoid;
      int r = tid >> 2;
      int c8 = (tid & 3) * 8;
      int grow = row0 + r;
      if (grow > nrows - 1) grow = nrows - 1;
      half8_t v = *(const half8_t*)&A[(size_t)grow * K + k0 + c8];
#pragma unroll
      for (int j = 0; j < 8; ++j) {
        float f = (float)v[j];
        __bf16 h = (__bf16)f;
        __bf16 l = (__bf16)(f - (float)h);
        As_hi[r][c8 + j] = __builtin_bit_cast(unsigned short, h);
        As_lo[r][c8 + j] = __builtin_bit_cast(unsigned short, l);
      }
    }
#pragma unroll
    for (int i = 0; i < NOUT / 64; ++i) {
      int n = i * 64 + (tid >> 2);
      int c8 = (tid & 3) * 8;
      *(uint4*)&Bs_hi[n][c8] = *(const uint4*)&Wt_hi[(size_t)n * K + k0 + c8];
      *(uint4*)&Bs_lo[n][c8] = *(const uint4*)&Wt_lo[(size_t)n * K + k0 + c8];
    }
    __syncthreads();

    bf16x8 ah = *(const bf16x8*)&As_hi[w * 16 + l16][quad * 8];
    bf16x8 al = *(const bf16x8*)&As_lo[w * 16 + l16][quad * 8];
#pragma unroll
    for (int t = 0; t < NT; ++t) {
      bf16x8 bh = *(const bf16x8*)&Bs_hi[t * 16 + l16][quad * 8];
      bf16x8 bl = *(const bf16x8*)&Bs_lo[t * 16 + l16][quad * 8];
      acc[t] = __builtin_amdgcn_mfma_f32_16x16x32_bf16(ah, bh, acc[t], 0, 0, 0);
      acc[t] = __builtin_amdgcn_mfma_f32_16x16x32_bf16(al, bh, acc[t], 0, 0, 0);
      acc[t] = __builtin_amdgcn_mfma_f32_16x16x32_bf16(ah, bl, acc[t], 0, 0, 0);
    }
    __syncthreads();
  }

#pragma unroll
  for (int t = 0; t < NT; ++t) {
#pragma unroll
    for (int r = 0; r < 4; ++r) {
      int grow = row0 + w * 16 + quad * 4 + r;
      if (grow < nrows) out[(size_t)grow * NOUT + t * 16 + l16] = (half_t)acc[t][r];
    }
  }
}

// ---------------- sliced aggregation ----------------
// grid = nchunks * NS blocks; slice = blockIdx & (NS-1) -> with round-robin
// blockIdx%8 -> XCD, each XCD touches only one 32-column slice (L2-resident).
// Wave handles 4 nodes sequentially; half-waves process alternating edges
// (2 edges x 4 unroll = 8 gathers in flight); halves combined via shfl_xor.
template <int D, int NS, bool RELU, typename OutT>
__global__ __launch_bounds__(256) void agg_s(const half_t* __restrict__ t,
                                             const int* __restrict__ offs,
                                             const int2* __restrict__ edges,
                                             const float* __restrict__ dinv,
                                             const float* __restrict__ bias,
                                             OutT* __restrict__ out, int n) {
  constexpr int SB = (NS == 4) ? 2 : 1;
  const int slice = blockIdx.x & (NS - 1);
  const int chunk = blockIdx.x >> SB;
  const int wv = threadIdx.x >> 6, lane = threadIdx.x & 63;
  const int hf = lane >> 5, fl = lane & 31;
  const int col = slice * 32 + fl;
  const half_t* tb = t + col;
  const float bv = bias[col];
  int node = chunk * 16 + wv * 4;
  int nend = min(node + 4, n);
  for (; node < nend; ++node) {
    int e0 = offs[node], e1 = offs[node + 1];
    float acc = 0.f;
    int e = e0 + hf;
    for (; e + 6 < e1; e += 8) {
      int2 d0 = edges[e], d1 = edges[e + 2], d2 = edges[e + 4], d3 = edges[e + 6];
      float v0 = (float)tb[(size_t)d0.x * D];
      float v1 = (float)tb[(size_t)d1.x * D];
      float v2 = (float)tb[(size_t)d2.x * D];
      float v3 = (float)tb[(size_t)d3.x * D];
      acc = fmaf(__int_as_float(d0.y), v0, acc);
      acc = fmaf(__int_as_float(d1.y), v1, acc);
      acc = fmaf(__int_as_float(d2.y), v2, acc);
      acc = fmaf(__int_as_float(d3.y), v3, acc);
    }
    for (; e < e1; e += 2) {
      int2 d = edges[e];
      acc = fmaf(__int_as_float(d.y), (float)tb[(size_t)d.x * D], acc);
    }
    acc += __shfl_xor(acc, 32);
    float di = dinv[node];
    float o = di * acc + di * di * (float)tb[(size_t)node * D] + bv;
    if (RELU) o = fmaxf(o, 0.f);
    if (hf == 0) out[(size_t)node * D + col] = (OutT)o;
  }
}

extern "C" void kernel_launch(void* const* d_in, const int* in_sizes, int n_in,
                              void* d_out, int out_size, void* d_ws, size_t ws_size,
                              hipStream_t stream) {
  const float* x = (const float*)d_in[0];
  const int* ei = (const int*)d_in[1];
  const float* gamma = (const float*)d_in[2];
  const float* beta = (const float*)d_in[3];
  const float* W1 = (const float*)d_in[4];
  const float* b1 = (const float*)d_in[5];
  const float* W2 = (const float*)d_in[6];
  const float* b2 = (const float*)d_in[7];
  const float* W3 = (const float*)d_in[8];
  const float* b3 = (const float*)d_in[9];
  float* out = (float*)d_out;

  const int N = in_sizes[0] / 256;
  const int E = in_sizes[1] / 2;
  const int* src = ei;
  const int* dst = ei + E;
  const int NB = (N + 255) >> 8;

  char* ws = (char*)d_ws;
  auto alloc = [&](size_t bytes) -> char* {
    char* p = ws;
    ws += (bytes + 255) & ~(size_t)255;
    return p;
  };
  int* bcnt = (int*)alloc(256 * 4);
  int* bbase = (int*)alloc(257 * 4);
  int* bcur = (int*)alloc(256 * 4);
  int2* binned = (int2*)alloc((size_t)E * 8);
  int* srcs = (int*)alloc((size_t)E * 4);
  int* offs = (int*)alloc((size_t)(N + 1) * 4);
  float* dinv = (float*)alloc((size_t)N * 4);
  int2* edges = (int2*)alloc((size_t)E * 8);
  float* mu = (float*)alloc((size_t)N * 4);
  float* rs = (float*)alloc((size_t)N * 4);
  half_t* t = (half_t*)alloc((size_t)N * 128 * 2);
  half_t* h = (half_t*)alloc((size_t)N * 128 * 2);
  unsigned short* W1t_hi = (unsigned short*)alloc(256 * 128 * 2);
  unsigned short* W1t_lo = (unsigned short*)alloc(256 * 128 * 2);
  unsigned short* W2t_hi = (unsigned short*)alloc(128 * 128 * 2);
  unsigned short* W2t_lo = (unsigned short*)alloc(128 * 128 * 2);
  unsigned short* W3t_hi = (unsigned short*)alloc(128 * 64 * 2);
  unsigned short* W3t_lo = (unsigned short*)alloc(128 * 64 * 2);

  // ---- CSR build via 2-level bucket sort ----
  zero_ctl<<<1, 256, 0, stream>>>(bcnt, 256);
  hist_bucket<<<256, 256, 0, stream>>>(dst, bcnt, E, NB);
  scan_buckets<<<1, 256, 0, stream>>>(bcnt, bbase, bcur, NB, E);
  scatter_bins<<<(E + CHUNK - 1) / CHUNK, 256, 0, stream>>>(src, dst, bcur, binned, E);
  sort_bucket<<<NB, 256, 0, stream>>>(binned, bbase, srcs, offs, dinv, N, NB, E);
  fill_w<<<(E + 255) / 256, 256, 0, stream>>>(srcs, dinv, edges, E);

  // ---- weight transpose + bf16 hi/lo split ----
  wsplit<<<(256 * 128 + 255) / 256, 256, 0, stream>>>(W1, W1t_hi, W1t_lo, 256, 128);
  wsplit<<<(128 * 128 + 255) / 256, 256, 0, stream>>>(W2, W2t_hi, W2t_lo, 128, 128);
  wsplit<<<(128 * 64 + 255) / 256, 256, 0, stream>>>(W3, W3t_hi, W3t_lo, 128, 64);

  // ---- layernorm stats ----
  ln_stats<<<(N + 3) / 4, 256, 0, stream>>>(x, mu, rs, N);

  const int gemm_blocks = (N + 63) / 64;
  const int nchunks = (N + 15) / 16;

  // ---- layer 1 ----
  gemm_mfma<256, 128, true, false><<<gemm_blocks, 256, 0, stream>>>(
      x, W1t_hi, W1t_lo, mu, rs, gamma, beta, t, N);
  agg_s<128, 4, true, half_t><<<nchunks * 4, 256, 0, stream>>>(t, offs, edges, dinv, b1, h, N);

  // ---- layer 2 ----
  gemm_mfma<128, 128, false, true><<<gemm_blocks, 256, 0, stream>>>(
      h, W2t_hi, W2t_lo, nullptr, nullptr, nullptr, nullptr, t, N);
  agg_s<128, 4, true, half_t><<<nchunks * 4, 256, 0, stream>>>(t, offs, edges, dinv, b2, h, N);

  // ---- layer 3 ----
  gemm_mfma<128, 64, false, true><<<gemm_blocks, 256, 0, stream>>>(
      h, W3t_hi, W3t_lo, nullptr, nullptr, nullptr, nullptr, t, N);
  agg_s<64, 2, false, float><<<nchunks * 2, 256, 0, stream>>>(t, offs, edges, dinv, b3, out, N);
}

// Round 6
// 313.884 us; speedup vs baseline: 1.4406x; 1.4406x over previous
//
#include <hip/hip_runtime.h>
#include <cstdint>
#include <cstddef>

// ---------------------------------------------------------------------------
// GCN encoder: z = GCN3( relu(GCN2( relu(GCN1( LN(x) )) )) )
// R6: R4 structure (best so far); agg edge loops deepened to 8 independent
//     gathers in flight (unroll x8 + x2 tail). R5's slicing reverted (XCD
//     affinity assumption failed; FETCH rose 1.44x).
// ---------------------------------------------------------------------------

typedef __attribute__((ext_vector_type(8))) __bf16 bf16x8;
typedef __attribute__((ext_vector_type(4))) float f32x4;
typedef _Float16 half_t;
typedef __attribute__((ext_vector_type(2))) _Float16 half2_t;
typedef __attribute__((ext_vector_type(8))) _Float16 half8_t;

// ---------------- CSR build: bucket sort by dst ----------------
__global__ void zero_ctl(int* __restrict__ p, int n) {
  int i = blockIdx.x * 256 + threadIdx.x;
  if (i < n) p[i] = 0;
}

__global__ __launch_bounds__(256) void hist_bucket(const int* __restrict__ dst,
                                                   int* __restrict__ bcnt, int E, int NB) {
  __shared__ int h[256];
  int t = threadIdx.x;
  h[t] = 0;
  __syncthreads();
  for (int e = blockIdx.x * 256 + t; e < E; e += gridDim.x * 256)
    atomicAdd(&h[dst[e] >> 8], 1);
  __syncthreads();
  if (t < NB && h[t]) atomicAdd(&bcnt[t], h[t]);
}

__global__ __launch_bounds__(256) void scan_buckets(const int* __restrict__ bcnt,
                                                    int* __restrict__ bbase,
                                                    int* __restrict__ bcur, int NB, int E) {
  __shared__ int tmp[256];
  int t = threadIdx.x;
  int v = (t < NB) ? bcnt[t] : 0;
  tmp[t] = v;
  __syncthreads();
  for (int off = 1; off < 256; off <<= 1) {
    int x = (t >= off) ? tmp[t - off] : 0;
    __syncthreads();
    tmp[t] += x;
    __syncthreads();
  }
  int excl = tmp[t] - v;
  if (t < NB) { bbase[t] = excl; bcur[t] = excl; }
  if (t == 0) bbase[NB] = E;
}

#define CHUNK 4096
__global__ __launch_bounds__(256) void scatter_bins(const int* __restrict__ src,
                                                    const int* __restrict__ dst,
                                                    int* __restrict__ bcur,
                                                    int2* __restrict__ binned, int E) {
  __shared__ int2 recs[CHUNK];
  __shared__ int hist[256], lbase[256], resv[256], cur[256];
  int t = threadIdx.x;
  int e0 = blockIdx.x * CHUNK;
  if (e0 >= E) return;
  int len = min(CHUNK, E - e0);
  hist[t] = 0;
  cur[t] = 0;
  __syncthreads();
  for (int i = t; i < len; i += 256) atomicAdd(&hist[dst[e0 + i] >> 8], 1);
  __syncthreads();
  int v = hist[t];
  lbase[t] = v;
  __syncthreads();
  for (int off = 1; off < 256; off <<= 1) {
    int x = (t >= off) ? lbase[t - off] : 0;
    __syncthreads();
    lbase[t] += x;
    __syncthreads();
  }
  int myexcl = lbase[t] - v;
  if (v) resv[t] = atomicAdd(&bcur[t], v);
  __syncthreads();
  lbase[t] = myexcl;
  __syncthreads();
  for (int i = t; i < len; i += 256) {
    int d = dst[e0 + i], s = src[e0 + i];
    int b = d >> 8;
    int r = atomicAdd(&cur[b], 1);
    recs[lbase[b] + r] = make_int2(s, d);
  }
  __syncthreads();
  for (int i = t; i < len; i += 256) {
    int2 rc = recs[i];
    int b = rc.y >> 8;
    binned[resv[b] + (i - lbase[b])] = rc;
  }
}

#define MAXB 8192
__global__ __launch_bounds__(256) void sort_bucket(const int2* __restrict__ binned,
                                                   const int* __restrict__ bbase,
                                                   int* __restrict__ srcs,
                                                   int* __restrict__ offs,
                                                   float* __restrict__ dinv,
                                                   int N, int NB, int E) {
  __shared__ int2 recs[MAXB];
  __shared__ unsigned short rnk[MAXB];
  __shared__ int sstage[MAXB];
  __shared__ int hist[256], nbase[256];
  int b = blockIdx.x, t = threadIdx.x;
  int base = bbase[b], end = bbase[b + 1];
  int L = end - base;
  if (L > MAXB) L = MAXB;
  hist[t] = 0;
  __syncthreads();
  for (int i = t; i < L; i += 256) {
    int2 rc = binned[base + i];
    recs[i] = rc;
    int r = atomicAdd(&hist[rc.y & 255], 1);
    rnk[i] = (unsigned short)r;
  }
  __syncthreads();
  int v = hist[t];
  nbase[t] = v;
  __syncthreads();
  for (int off = 1; off < 256; off <<= 1) {
    int x = (t >= off) ? nbase[t - off] : 0;
    __syncthreads();
    nbase[t] += x;
    __syncthreads();
  }
  int excl = nbase[t] - v;
  __syncthreads();
  nbase[t] = excl;
  int node = (b << 8) + t;
  if (node < N) {
    offs[node] = base + excl;
    dinv[node] = rsqrtf(1.0f + (float)v);
  }
  if (b == NB - 1 && t == 0) offs[N] = E;
  __syncthreads();
  for (int i = t; i < L; i += 256) {
    int2 rc = recs[i];
    sstage[nbase[rc.y & 255] + rnk[i]] = rc.x;
  }
  __syncthreads();
  for (int i = t; i < L; i += 256) srcs[base + i] = sstage[i];
}

__global__ void fill_w(const int* __restrict__ srcs, const float* __restrict__ dinv,
                       int2* __restrict__ edges, int E) {
  int e = blockIdx.x * 256 + threadIdx.x;
  if (e < E) {
    int s = srcs[e];
    edges[e] = make_int2(s, __float_as_int(dinv[s]));
  }
}

// ---------------- LN stats ----------------
__global__ void ln_stats(const float* __restrict__ x, float* __restrict__ mu,
                         float* __restrict__ rs, int n) {
  int gid = blockIdx.x * blockDim.x + threadIdx.x;
  int wv = gid >> 6, lane = gid & 63;
  if (wv >= n) return;
  const float4* row = (const float4*)(x + (size_t)wv * 256);
  float4 v = row[lane];
  float s = v.x + v.y + v.z + v.w;
  float s2 = v.x * v.x + v.y * v.y + v.z * v.z + v.w * v.w;
  for (int off = 32; off > 0; off >>= 1) {
    s += __shfl_down(s, off);
    s2 += __shfl_down(s2, off);
  }
  if (lane == 0) {
    float m = s * (1.0f / 256.0f);
    float var = s2 * (1.0f / 256.0f) - m * m;
    mu[wv] = m;
    rs[wv] = rsqrtf(var + 1e-5f);
  }
}

// W[K][NOUT] fp32 -> Wt_hi/Wt_lo[NOUT][K] bf16 bit patterns (B-operand layout)
__global__ void wsplit(const float* __restrict__ W, unsigned short* __restrict__ Wt_hi,
                       unsigned short* __restrict__ Wt_lo, int K, int NOUT) {
  int idx = blockIdx.x * 256 + threadIdx.x;
  if (idx >= K * NOUT) return;
  int k = idx / NOUT, n = idx % NOUT;
  float v = W[idx];
  __bf16 h = (__bf16)v;
  __bf16 l = (__bf16)(v - (float)h);
  Wt_hi[(size_t)n * K + k] = __builtin_bit_cast(unsigned short, h);
  Wt_lo[(size_t)n * K + k] = __builtin_bit_cast(unsigned short, l);
}

// out16[nrows x NOUT] = A[nrows x K] * W[K x NOUT] via bf16x3 MFMA.
template <int K, int NOUT, bool LN, bool A_FP16>
__launch_bounds__(256)
__global__ void gemm_mfma(const void* __restrict__ Avoid,
                          const unsigned short* __restrict__ Wt_hi,
                          const unsigned short* __restrict__ Wt_lo,
                          const float* __restrict__ mu, const float* __restrict__ rs,
                          const float* __restrict__ gamma, const float* __restrict__ beta,
                          half_t* __restrict__ out, int nrows) {
  constexpr int BM = 64, BK = 32;
  constexpr int NT = NOUT / 16;
  __shared__ unsigned short As_hi[BM][BK];
  __shared__ unsigned short As_lo[BM][BK];
  __shared__ unsigned short Bs_hi[NOUT][BK];
  __shared__ unsigned short Bs_lo[NOUT][BK];

  const int tid = threadIdx.x;
  const int lane = tid & 63;
  const int w = tid >> 6;
  const int quad = lane >> 4;
  const int l16 = lane & 15;
  const int row0 = blockIdx.x * BM;

  f32x4 acc[NT];
#pragma unroll
  for (int t = 0; t < NT; ++t) acc[t] = (f32x4){0.f, 0.f, 0.f, 0.f};

  for (int k0 = 0; k0 < K; k0 += BK) {
    if (!A_FP16) {
      const float* A = (const float*)Avoid;
#pragma unroll
      for (int i = 0; i < 2; ++i) {
        int r = i * 32 + (tid >> 3);
        int c4 = (tid & 7) * 4;
        int grow = row0 + r;
        if (grow > nrows - 1) grow = nrows - 1;
        float4 v = *(const float4*)&A[(size_t)grow * K + k0 + c4];
        if (LN) {
          float m = mu[grow], s = rs[grow];
          float4 g = *(const float4*)&gamma[k0 + c4];
          float4 b = *(const float4*)&beta[k0 + c4];
          v.x = (v.x - m) * s * g.x + b.x;
          v.y = (v.y - m) * s * g.y + b.y;
          v.z = (v.z - m) * s * g.z + b.z;
          v.w = (v.w - m) * s * g.w + b.w;
        }
        float vv[4] = {v.x, v.y, v.z, v.w};
#pragma unroll
        for (int j = 0; j < 4; ++j) {
          __bf16 h = (__bf16)vv[j];
          __bf16 l = (__bf16)(vv[j] - (float)h);
          As_hi[r][c4 + j] = __builtin_bit_cast(unsigned short, h);
          As_lo[r][c4 + j] = __builtin_bit_cast(unsigned short, l);
        }
      }
    } else {
      const half_t* A = (const half_t*)Avoid;
      int r = tid >> 2;
      int c8 = (tid & 3) * 8;
      int grow = row0 + r;
      if (grow > nrows - 1) grow = nrows - 1;
      half8_t v = *(const half8_t*)&A[(size_t)grow * K + k0 + c8];
#pragma unroll
      for (int j = 0; j < 8; ++j) {
        float f = (float)v[j];
        __bf16 h = (__bf16)f;
        __bf16 l = (__bf16)(f - (float)h);
        As_hi[r][c8 + j] = __builtin_bit_cast(unsigned short, h);
        As_lo[r][c8 + j] = __builtin_bit_cast(unsigned short, l);
      }
    }
#pragma unroll
    for (int i = 0; i < NOUT / 64; ++i) {
      int n = i * 64 + (tid >> 2);
      int c8 = (tid & 3) * 8;
      *(uint4*)&Bs_hi[n][c8] = *(const uint4*)&Wt_hi[(size_t)n * K + k0 + c8];
      *(uint4*)&Bs_lo[n][c8] = *(const uint4*)&Wt_lo[(size_t)n * K + k0 + c8];
    }
    __syncthreads();

    bf16x8 ah = *(const bf16x8*)&As_hi[w * 16 + l16][quad * 8];
    bf16x8 al = *(const bf16x8*)&As_lo[w * 16 + l16][quad * 8];
#pragma unroll
    for (int t = 0; t < NT; ++t) {
      bf16x8 bh = *(const bf16x8*)&Bs_hi[t * 16 + l16][quad * 8];
      bf16x8 bl = *(const bf16x8*)&Bs_lo[t * 16 + l16][quad * 8];
      acc[t] = __builtin_amdgcn_mfma_f32_16x16x32_bf16(ah, bh, acc[t], 0, 0, 0);
      acc[t] = __builtin_amdgcn_mfma_f32_16x16x32_bf16(al, bh, acc[t], 0, 0, 0);
      acc[t] = __builtin_amdgcn_mfma_f32_16x16x32_bf16(ah, bl, acc[t], 0, 0, 0);
    }
    __syncthreads();
  }

#pragma unroll
  for (int t = 0; t < NT; ++t) {
#pragma unroll
    for (int r = 0; r < 4; ++r) {
      int grow = row0 + w * 16 + quad * 4 + r;
      if (grow < nrows) out[(size_t)grow * NOUT + t * 16 + l16] = (half_t)acc[t][r];
    }
  }
}

// ---------------- aggregation (wave per dst node, x8 unrolled gathers) ------
__global__ void agg128_h(const half_t* __restrict__ t, const int* __restrict__ offs,
                         const int2* __restrict__ edges, const float* __restrict__ dinv,
                         const float* __restrict__ bias, half_t* __restrict__ out, int n) {
  int gid = blockIdx.x * blockDim.x + threadIdx.x;
  int wv = gid >> 6, lane = gid & 63;
  if (wv >= n) return;
  int e0 = offs[wv], e1 = offs[wv + 1];
  float ax = 0.f, ay = 0.f;
  int e = e0;
  for (; e + 7 < e1; e += 8) {
    int2 d0 = edges[e], d1 = edges[e + 1], d2 = edges[e + 2], d3 = edges[e + 3];
    int2 d4 = edges[e + 4], d5 = edges[e + 5], d6 = edges[e + 6], d7 = edges[e + 7];
    half2_t v0 = *(const half2_t*)(t + ((size_t)d0.x << 7) + lane * 2);
    half2_t v1 = *(const half2_t*)(t + ((size_t)d1.x << 7) + lane * 2);
    half2_t v2 = *(const half2_t*)(t + ((size_t)d2.x << 7) + lane * 2);
    half2_t v3 = *(const half2_t*)(t + ((size_t)d3.x << 7) + lane * 2);
    half2_t v4 = *(const half2_t*)(t + ((size_t)d4.x << 7) + lane * 2);
    half2_t v5 = *(const half2_t*)(t + ((size_t)d5.x << 7) + lane * 2);
    half2_t v6 = *(const half2_t*)(t + ((size_t)d6.x << 7) + lane * 2);
    half2_t v7 = *(const half2_t*)(t + ((size_t)d7.x << 7) + lane * 2);
    float w0 = __int_as_float(d0.y), w1 = __int_as_float(d1.y);
    float w2 = __int_as_float(d2.y), w3 = __int_as_float(d3.y);
    float w4 = __int_as_float(d4.y), w5 = __int_as_float(d5.y);
    float w6 = __int_as_float(d6.y), w7 = __int_as_float(d7.y);
    ax = fmaf(w0, (float)v0[0], ax); ay = fmaf(w0, (float)v0[1], ay);
    ax = fmaf(w1, (float)v1[0], ax); ay = fmaf(w1, (float)v1[1], ay);
    ax = fmaf(w2, (float)v2[0], ax); ay = fmaf(w2, (float)v2[1], ay);
    ax = fmaf(w3, (float)v3[0], ax); ay = fmaf(w3, (float)v3[1], ay);
    ax = fmaf(w4, (float)v4[0], ax); ay = fmaf(w4, (float)v4[1], ay);
    ax = fmaf(w5, (float)v5[0], ax); ay = fmaf(w5, (float)v5[1], ay);
    ax = fmaf(w6, (float)v6[0], ax); ay = fmaf(w6, (float)v6[1], ay);
    ax = fmaf(w7, (float)v7[0], ax); ay = fmaf(w7, (float)v7[1], ay);
  }
  for (; e + 1 < e1; e += 2) {
    int2 d0 = edges[e], d1 = edges[e + 1];
    half2_t v0 = *(const half2_t*)(t + ((size_t)d0.x << 7) + lane * 2);
    half2_t v1 = *(const half2_t*)(t + ((size_t)d1.x << 7) + lane * 2);
    float w0 = __int_as_float(d0.y), w1 = __int_as_float(d1.y);
    ax = fmaf(w0, (float)v0[0], ax); ay = fmaf(w0, (float)v0[1], ay);
    ax = fmaf(w1, (float)v1[0], ax); ay = fmaf(w1, (float)v1[1], ay);
  }
  if (e < e1) {
    int2 ed = edges[e];
    half2_t v = *(const half2_t*)(t + ((size_t)ed.x << 7) + lane * 2);
    float w = __int_as_float(ed.y);
    ax = fmaf(w, (float)v[0], ax);
    ay = fmaf(w, (float)v[1], ay);
  }
  float di = dinv[wv];
  half2_t sv = *(const half2_t*)(t + ((size_t)wv << 7) + lane * 2);
  float2 bv = *(const float2*)(bias + lane * 2);
  float ox = di * ax + di * di * (float)sv[0] + bv.x;
  float oy = di * ay + di * di * (float)sv[1] + bv.y;
  ox = fmaxf(ox, 0.f);
  oy = fmaxf(oy, 0.f);
  half2_t o;
  o[0] = (half_t)ox;
  o[1] = (half_t)oy;
  *(half2_t*)(out + ((size_t)wv << 7) + lane * 2) = o;
}

__global__ void agg64_h(const half_t* __restrict__ t, const int* __restrict__ offs,
                        const int2* __restrict__ edges, const float* __restrict__ dinv,
                        const float* __restrict__ bias, float* __restrict__ out, int n) {
  int gid = blockIdx.x * blockDim.x + threadIdx.x;
  int wv = gid >> 6, lane = gid & 63;
  if (wv >= n) return;
  int e0 = offs[wv], e1 = offs[wv + 1];
  float a = 0.f;
  int e = e0;
  for (; e + 7 < e1; e += 8) {
    int2 d0 = edges[e], d1 = edges[e + 1], d2 = edges[e + 2], d3 = edges[e + 3];
    int2 d4 = edges[e + 4], d5 = edges[e + 5], d6 = edges[e + 6], d7 = edges[e + 7];
    float v0 = (float)t[((size_t)d0.x << 6) + lane];
    float v1 = (float)t[((size_t)d1.x << 6) + lane];
    float v2 = (float)t[((size_t)d2.x << 6) + lane];
    float v3 = (float)t[((size_t)d3.x << 6) + lane];
    float v4 = (float)t[((size_t)d4.x << 6) + lane];
    float v5 = (float)t[((size_t)d5.x << 6) + lane];
    float v6 = (float)t[((size_t)d6.x << 6) + lane];
    float v7 = (float)t[((size_t)d7.x << 6) + lane];
    a = fmaf(__int_as_float(d0.y), v0, a);
    a = fmaf(__int_as_float(d1.y), v1, a);
    a = fmaf(__int_as_float(d2.y), v2, a);
    a = fmaf(__int_as_float(d3.y), v3, a);
    a = fmaf(__int_as_float(d4.y), v4, a);
    a = fmaf(__int_as_float(d5.y), v5, a);
    a = fmaf(__int_as_float(d6.y), v6, a);
    a = fmaf(__int_as_float(d7.y), v7, a);
  }
  for (; e + 1 < e1; e += 2) {
    int2 d0 = edges[e], d1 = edges[e + 1];
    a = fmaf(__int_as_float(d0.y), (float)t[((size_t)d0.x << 6) + lane], a);
    a = fmaf(__int_as_float(d1.y), (float)t[((size_t)d1.x << 6) + lane], a);
  }
  if (e < e1) {
    int2 ed = edges[e];
    a = fmaf(__int_as_float(ed.y), (float)t[((size_t)ed.x << 6) + lane], a);
  }
  float di = dinv[wv];
  float v = di * a + di * di * (float)t[((size_t)wv << 6) + lane] + bias[lane];
  out[((size_t)wv << 6) + lane] = v;
}

extern "C" void kernel_launch(void* const* d_in, const int* in_sizes, int n_in,
                              void* d_out, int out_size, void* d_ws, size_t ws_size,
                              hipStream_t stream) {
  const float* x = (const float*)d_in[0];
  const int* ei = (const int*)d_in[1];
  const float* gamma = (const float*)d_in[2];
  const float* beta = (const float*)d_in[3];
  const float* W1 = (const float*)d_in[4];
  const float* b1 = (const float*)d_in[5];
  const float* W2 = (const float*)d_in[6];
  const float* b2 = (const float*)d_in[7];
  const float* W3 = (const float*)d_in[8];
  const float* b3 = (const float*)d_in[9];
  float* out = (float*)d_out;

  const int N = in_sizes[0] / 256;
  const int E = in_sizes[1] / 2;
  const int* src = ei;
  const int* dst = ei + E;
  const int NB = (N + 255) >> 8;

  char* ws = (char*)d_ws;
  auto alloc = [&](size_t bytes) -> char* {
    char* p = ws;
    ws += (bytes + 255) & ~(size_t)255;
    return p;
  };
  int* bcnt = (int*)alloc(256 * 4);
  int* bbase = (int*)alloc(257 * 4);
  int* bcur = (int*)alloc(256 * 4);
  int2* binned = (int2*)alloc((size_t)E * 8);
  int* srcs = (int*)alloc((size_t)E * 4);
  int* offs = (int*)alloc((size_t)(N + 1) * 4);
  float* dinv = (float*)alloc((size_t)N * 4);
  int2* edges = (int2*)alloc((size_t)E * 8);
  float* mu = (float*)alloc((size_t)N * 4);
  float* rs = (float*)alloc((size_t)N * 4);
  half_t* t = (half_t*)alloc((size_t)N * 128 * 2);
  half_t* h = (half_t*)alloc((size_t)N * 128 * 2);
  unsigned short* W1t_hi = (unsigned short*)alloc(256 * 128 * 2);
  unsigned short* W1t_lo = (unsigned short*)alloc(256 * 128 * 2);
  unsigned short* W2t_hi = (unsigned short*)alloc(128 * 128 * 2);
  unsigned short* W2t_lo = (unsigned short*)alloc(128 * 128 * 2);
  unsigned short* W3t_hi = (unsigned short*)alloc(128 * 64 * 2);
  unsigned short* W3t_lo = (unsigned short*)alloc(128 * 64 * 2);

  // ---- CSR build via 2-level bucket sort ----
  zero_ctl<<<1, 256, 0, stream>>>(bcnt, 256);
  hist_bucket<<<256, 256, 0, stream>>>(dst, bcnt, E, NB);
  scan_buckets<<<1, 256, 0, stream>>>(bcnt, bbase, bcur, NB, E);
  scatter_bins<<<(E + CHUNK - 1) / CHUNK, 256, 0, stream>>>(src, dst, bcur, binned, E);
  sort_bucket<<<NB, 256, 0, stream>>>(binned, bbase, srcs, offs, dinv, N, NB, E);
  fill_w<<<(E + 255) / 256, 256, 0, stream>>>(srcs, dinv, edges, E);

  // ---- weight transpose + bf16 hi/lo split ----
  wsplit<<<(256 * 128 + 255) / 256, 256, 0, stream>>>(W1, W1t_hi, W1t_lo, 256, 128);
  wsplit<<<(128 * 128 + 255) / 256, 256, 0, stream>>>(W2, W2t_hi, W2t_lo, 128, 128);
  wsplit<<<(128 * 64 + 255) / 256, 256, 0, stream>>>(W3, W3t_hi, W3t_lo, 128, 64);

  // ---- layernorm stats ----
  ln_stats<<<(N + 3) / 4, 256, 0, stream>>>(x, mu, rs, N);

  const int gemm_blocks = (N + 63) / 64;
  const int agg_blocks = (N + 3) / 4;

  // ---- layer 1 ----
  gemm_mfma<256, 128, true, false><<<gemm_blocks, 256, 0, stream>>>(
      x, W1t_hi, W1t_lo, mu, rs, gamma, beta, t, N);
  agg128_h<<<agg_blocks, 256, 0, stream>>>(t, offs, edges, dinv, b1, h, N);

  // ---- layer 2 ----
  gemm_mfma<128, 128, false, true><<<gemm_blocks, 256, 0, stream>>>(
      h, W2t_hi, W2t_lo, nullptr, nullptr, nullptr, nullptr, t, N);
  agg128_h<<<agg_blocks, 256, 0, stream>>>(t, offs, edges, dinv, b2, h, N);

  // ---- layer 3 ----
  gemm_mfma<128, 64, false, true><<<gemm_blocks, 256, 0, stream>>>(
      h, W3t_hi, W3t_lo, nullptr, nullptr, nullptr, nullptr, t, N);
  agg64_h<<<agg_blocks, 256, 0, stream>>>(t, offs, edges, dinv, b3, out, N);
}

// Round 7
// 301.796 us; speedup vs baseline: 1.4983x; 1.0401x over previous
//
#include <hip/hip_runtime.h>
#include <cstdint>
#include <cstddef>

// ---------------------------------------------------------------------------
// GCN encoder: z = GCN3( relu(GCN2( relu(GCN1( LN(x) )) )) )
// R7: quarter-wave gathers in aggregation — one global_load_dwordx4 serves
//     4 rows (16 lines in flight/instruction); 16 rows in flight per wave.
//     Combine via shfl_xor(16|32). agg64 uses eighth-waves (8 rows/instr).
//     Everything else identical to R6 (best: 313.9 us).
// ---------------------------------------------------------------------------

typedef __attribute__((ext_vector_type(8))) __bf16 bf16x8;
typedef __attribute__((ext_vector_type(4))) float f32x4;
typedef _Float16 half_t;
typedef __attribute__((ext_vector_type(8))) _Float16 half8_t;

// ---------------- CSR build: bucket sort by dst ----------------
__global__ void zero_ctl(int* __restrict__ p, int n) {
  int i = blockIdx.x * 256 + threadIdx.x;
  if (i < n) p[i] = 0;
}

__global__ __launch_bounds__(256) void hist_bucket(const int* __restrict__ dst,
                                                   int* __restrict__ bcnt, int E, int NB) {
  __shared__ int h[256];
  int t = threadIdx.x;
  h[t] = 0;
  __syncthreads();
  for (int e = blockIdx.x * 256 + t; e < E; e += gridDim.x * 256)
    atomicAdd(&h[dst[e] >> 8], 1);
  __syncthreads();
  if (t < NB && h[t]) atomicAdd(&bcnt[t], h[t]);
}

__global__ __launch_bounds__(256) void scan_buckets(const int* __restrict__ bcnt,
                                                    int* __restrict__ bbase,
                                                    int* __restrict__ bcur, int NB, int E) {
  __shared__ int tmp[256];
  int t = threadIdx.x;
  int v = (t < NB) ? bcnt[t] : 0;
  tmp[t] = v;
  __syncthreads();
  for (int off = 1; off < 256; off <<= 1) {
    int x = (t >= off) ? tmp[t - off] : 0;
    __syncthreads();
    tmp[t] += x;
    __syncthreads();
  }
  int excl = tmp[t] - v;
  if (t < NB) { bbase[t] = excl; bcur[t] = excl; }
  if (t == 0) bbase[NB] = E;
}

#define CHUNK 4096
__global__ __launch_bounds__(256) void scatter_bins(const int* __restrict__ src,
                                                    const int* __restrict__ dst,
                                                    int* __restrict__ bcur,
                                                    int2* __restrict__ binned, int E) {
  __shared__ int2 recs[CHUNK];
  __shared__ int hist[256], lbase[256], resv[256], cur[256];
  int t = threadIdx.x;
  int e0 = blockIdx.x * CHUNK;
  if (e0 >= E) return;
  int len = min(CHUNK, E - e0);
  hist[t] = 0;
  cur[t] = 0;
  __syncthreads();
  for (int i = t; i < len; i += 256) atomicAdd(&hist[dst[e0 + i] >> 8], 1);
  __syncthreads();
  int v = hist[t];
  lbase[t] = v;
  __syncthreads();
  for (int off = 1; off < 256; off <<= 1) {
    int x = (t >= off) ? lbase[t - off] : 0;
    __syncthreads();
    lbase[t] += x;
    __syncthreads();
  }
  int myexcl = lbase[t] - v;
  if (v) resv[t] = atomicAdd(&bcur[t], v);
  __syncthreads();
  lbase[t] = myexcl;
  __syncthreads();
  for (int i = t; i < len; i += 256) {
    int d = dst[e0 + i], s = src[e0 + i];
    int b = d >> 8;
    int r = atomicAdd(&cur[b], 1);
    recs[lbase[b] + r] = make_int2(s, d);
  }
  __syncthreads();
  for (int i = t; i < len; i += 256) {
    int2 rc = recs[i];
    int b = rc.y >> 8;
    binned[resv[b] + (i - lbase[b])] = rc;
  }
}

#define MAXB 8192
__global__ __launch_bounds__(256) void sort_bucket(const int2* __restrict__ binned,
                                                   const int* __restrict__ bbase,
                                                   int* __restrict__ srcs,
                                                   int* __restrict__ offs,
                                                   float* __restrict__ dinv,
                                                   int N, int NB, int E) {
  __shared__ int2 recs[MAXB];
  __shared__ unsigned short rnk[MAXB];
  __shared__ int sstage[MAXB];
  __shared__ int hist[256], nbase[256];
  int b = blockIdx.x, t = threadIdx.x;
  int base = bbase[b], end = bbase[b + 1];
  int L = end - base;
  if (L > MAXB) L = MAXB;
  hist[t] = 0;
  __syncthreads();
  for (int i = t; i < L; i += 256) {
    int2 rc = binned[base + i];
    recs[i] = rc;
    int r = atomicAdd(&hist[rc.y & 255], 1);
    rnk[i] = (unsigned short)r;
  }
  __syncthreads();
  int v = hist[t];
  nbase[t] = v;
  __syncthreads();
  for (int off = 1; off < 256; off <<= 1) {
    int x = (t >= off) ? nbase[t - off] : 0;
    __syncthreads();
    nbase[t] += x;
    __syncthreads();
  }
  int excl = nbase[t] - v;
  __syncthreads();
  nbase[t] = excl;
  int node = (b << 8) + t;
  if (node < N) {
    offs[node] = base + excl;
    dinv[node] = rsqrtf(1.0f + (float)v);
  }
  if (b == NB - 1 && t == 0) offs[N] = E;
  __syncthreads();
  for (int i = t; i < L; i += 256) {
    int2 rc = recs[i];
    sstage[nbase[rc.y & 255] + rnk[i]] = rc.x;
  }
  __syncthreads();
  for (int i = t; i < L; i += 256) srcs[base + i] = sstage[i];
}

__global__ void fill_w(const int* __restrict__ srcs, const float* __restrict__ dinv,
                       int2* __restrict__ edges, int E) {
  int e = blockIdx.x * 256 + threadIdx.x;
  if (e < E) {
    int s = srcs[e];
    edges[e] = make_int2(s, __float_as_int(dinv[s]));
  }
}

// ---------------- LN stats ----------------
__global__ void ln_stats(const float* __restrict__ x, float* __restrict__ mu,
                         float* __restrict__ rs, int n) {
  int gid = blockIdx.x * blockDim.x + threadIdx.x;
  int wv = gid >> 6, lane = gid & 63;
  if (wv >= n) return;
  const float4* row = (const float4*)(x + (size_t)wv * 256);
  float4 v = row[lane];
  float s = v.x + v.y + v.z + v.w;
  float s2 = v.x * v.x + v.y * v.y + v.z * v.z + v.w * v.w;
  for (int off = 32; off > 0; off >>= 1) {
    s += __shfl_down(s, off);
    s2 += __shfl_down(s2, off);
  }
  if (lane == 0) {
    float m = s * (1.0f / 256.0f);
    float var = s2 * (1.0f / 256.0f) - m * m;
    mu[wv] = m;
    rs[wv] = rsqrtf(var + 1e-5f);
  }
}

// W[K][NOUT] fp32 -> Wt_hi/Wt_lo[NOUT][K] bf16 bit patterns (B-operand layout)
__global__ void wsplit(const float* __restrict__ W, unsigned short* __restrict__ Wt_hi,
                       unsigned short* __restrict__ Wt_lo, int K, int NOUT) {
  int idx = blockIdx.x * 256 + threadIdx.x;
  if (idx >= K * NOUT) return;
  int k = idx / NOUT, n = idx % NOUT;
  float v = W[idx];
  __bf16 h = (__bf16)v;
  __bf16 l = (__bf16)(v - (float)h);
  Wt_hi[(size_t)n * K + k] = __builtin_bit_cast(unsigned short, h);
  Wt_lo[(size_t)n * K + k] = __builtin_bit_cast(unsigned short, l);
}

// out16[nrows x NOUT] = A[nrows x K] * W[K x NOUT] via bf16x3 MFMA.
template <int K, int NOUT, bool LN, bool A_FP16>
__launch_bounds__(256)
__global__ void gemm_mfma(const void* __restrict__ Avoid,
                          const unsigned short* __restrict__ Wt_hi,
                          const unsigned short* __restrict__ Wt_lo,
                          const float* __restrict__ mu, const float* __restrict__ rs,
                          const float* __restrict__ gamma, const float* __restrict__ beta,
                          half_t* __restrict__ out, int nrows) {
  constexpr int BM = 64, BK = 32;
  constexpr int NT = NOUT / 16;
  __shared__ unsigned short As_hi[BM][BK];
  __shared__ unsigned short As_lo[BM][BK];
  __shared__ unsigned short Bs_hi[NOUT][BK];
  __shared__ unsigned short Bs_lo[NOUT][BK];

  const int tid = threadIdx.x;
  const int lane = tid & 63;
  const int w = tid >> 6;
  const int quad = lane >> 4;
  const int l16 = lane & 15;
  const int row0 = blockIdx.x * BM;

  f32x4 acc[NT];
#pragma unroll
  for (int t = 0; t < NT; ++t) acc[t] = (f32x4){0.f, 0.f, 0.f, 0.f};

  for (int k0 = 0; k0 < K; k0 += BK) {
    if (!A_FP16) {
      const float* A = (const float*)Avoid;
#pragma unroll
      for (int i = 0; i < 2; ++i) {
        int r = i * 32 + (tid >> 3);
        int c4 = (tid & 7) * 4;
        int grow = row0 + r;
        if (grow > nrows - 1) grow = nrows - 1;
        float4 v = *(const float4*)&A[(size_t)grow * K + k0 + c4];
        if (LN) {
          float m = mu[grow], s = rs[grow];
          float4 g = *(const float4*)&gamma[k0 + c4];
          float4 b = *(const float4*)&beta[k0 + c4];
          v.x = (v.x - m) * s * g.x + b.x;
          v.y = (v.y - m) * s * g.y + b.y;
          v.z = (v.z - m) * s * g.z + b.z;
          v.w = (v.w - m) * s * g.w + b.w;
        }
        float vv[4] = {v.x, v.y, v.z, v.w};
#pragma unroll
        for (int j = 0; j < 4; ++j) {
          __bf16 h = (__bf16)vv[j];
          __bf16 l = (__bf16)(vv[j] - (float)h);
          As_hi[r][c4 + j] = __builtin_bit_cast(unsigned short, h);
          As_lo[r][c4 + j] = __builtin_bit_cast(unsigned short, l);
        }
      }
    } else {
      const half_t* A = (const half_t*)Avoid;
      int r = tid >> 2;
      int c8 = (tid & 3) * 8;
      int grow = row0 + r;
      if (grow > nrows - 1) grow = nrows - 1;
      half8_t v = *(const half8_t*)&A[(size_t)grow * K + k0 + c8];
#pragma unroll
      for (int j = 0; j < 8; ++j) {
        float f = (float)v[j];
        __bf16 h = (__bf16)f;
        __bf16 l = (__bf16)(f - (float)h);
        As_hi[r][c8 + j] = __builtin_bit_cast(unsigned short, h);
        As_lo[r][c8 + j] = __builtin_bit_cast(unsigned short, l);
      }
    }
#pragma unroll
    for (int i = 0; i < NOUT / 64; ++i) {
      int n = i * 64 + (tid >> 2);
      int c8 = (tid & 3) * 8;
      *(uint4*)&Bs_hi[n][c8] = *(const uint4*)&Wt_hi[(size_t)n * K + k0 + c8];
      *(uint4*)&Bs_lo[n][c8] = *(const uint4*)&Wt_lo[(size_t)n * K + k0 + c8];
    }
    __syncthreads();

    bf16x8 ah = *(const bf16x8*)&As_hi[w * 16 + l16][quad * 8];
    bf16x8 al = *(const bf16x8*)&As_lo[w * 16 + l16][quad * 8];
#pragma unroll
    for (int t = 0; t < NT; ++t) {
      bf16x8 bh = *(const bf16x8*)&Bs_hi[t * 16 + l16][quad * 8];
      bf16x8 bl = *(const bf16x8*)&Bs_lo[t * 16 + l16][quad * 8];
      acc[t] = __builtin_amdgcn_mfma_f32_16x16x32_bf16(ah, bh, acc[t], 0, 0, 0);
      acc[t] = __builtin_amdgcn_mfma_f32_16x16x32_bf16(al, bh, acc[t], 0, 0, 0);
      acc[t] = __builtin_amdgcn_mfma_f32_16x16x32_bf16(ah, bl, acc[t], 0, 0, 0);
    }
    __syncthreads();
  }

#pragma unroll
  for (int t = 0; t < NT; ++t) {
#pragma unroll
    for (int r = 0; r < 4; ++r) {
      int grow = row0 + w * 16 + quad * 4 + r;
      if (grow < nrows) out[(size_t)grow * NOUT + t * 16 + l16] = (half_t)acc[t][r];
    }
  }
}

// ---------------- aggregation: quarter-wave gathers ----------------
// D=128: 16 lanes x 16B = one row; one dwordx4 instr gathers 4 rows.
// Unroll x4 -> 16 rows in flight per wave. Combine via shfl_xor(16|32).
__global__ __launch_bounds__(256) void agg128_h(const half_t* __restrict__ t,
                                                const int* __restrict__ offs,
                                                const int2* __restrict__ edges,
                                                const float* __restrict__ dinv,
                                                const float* __restrict__ bias,
                                                half_t* __restrict__ out, int n) {
  int gid = blockIdx.x * blockDim.x + threadIdx.x;
  int node = gid >> 6, lane = gid & 63;
  if (node >= n) return;
  int qw = lane >> 4;   // quarter id 0..3
  int fl = lane & 15;   // lane in quarter; columns fl*8 .. fl*8+7
  int e0 = offs[node], e1 = offs[node + 1];
  float acc[8] = {0.f, 0.f, 0.f, 0.f, 0.f, 0.f, 0.f, 0.f};
  int e = e0 + qw;
  for (; e + 12 < e1; e += 16) {
    int2 da = edges[e], db = edges[e + 4], dc = edges[e + 8], dd = edges[e + 12];
    half8_t va = *(const half8_t*)(t + ((size_t)da.x << 7) + fl * 8);
    half8_t vb = *(const half8_t*)(t + ((size_t)db.x << 7) + fl * 8);
    half8_t vc = *(const half8_t*)(t + ((size_t)dc.x << 7) + fl * 8);
    half8_t vd = *(const half8_t*)(t + ((size_t)dd.x << 7) + fl * 8);
    float wa = __int_as_float(da.y), wb = __int_as_float(db.y);
    float wc = __int_as_float(dc.y), wd = __int_as_float(dd.y);
#pragma unroll
    for (int j = 0; j < 8; ++j) {
      acc[j] = fmaf(wa, (float)va[j], acc[j]);
      acc[j] = fmaf(wb, (float)vb[j], acc[j]);
      acc[j] = fmaf(wc, (float)vc[j], acc[j]);
      acc[j] = fmaf(wd, (float)vd[j], acc[j]);
    }
  }
  for (; e < e1; e += 4) {
    int2 d = edges[e];
    half8_t v = *(const half8_t*)(t + ((size_t)d.x << 7) + fl * 8);
    float w = __int_as_float(d.y);
#pragma unroll
    for (int j = 0; j < 8; ++j) acc[j] = fmaf(w, (float)v[j], acc[j]);
  }
#pragma unroll
  for (int j = 0; j < 8; ++j) {
    acc[j] += __shfl_xor(acc[j], 16);
    acc[j] += __shfl_xor(acc[j], 32);
  }
  if (qw == 0) {
    float di = dinv[node];
    float dii = di * di;
    half8_t sv = *(const half8_t*)(t + ((size_t)node << 7) + fl * 8);
    float4 b0 = *(const float4*)(bias + fl * 8);
    float4 b1 = *(const float4*)(bias + fl * 8 + 4);
    float bb[8] = {b0.x, b0.y, b0.z, b0.w, b1.x, b1.y, b1.z, b1.w};
    half8_t o;
#pragma unroll
    for (int j = 0; j < 8; ++j) {
      float v = di * acc[j] + dii * (float)sv[j] + bb[j];
      o[j] = (half_t)fmaxf(v, 0.f);
    }
    *(half8_t*)(out + ((size_t)node << 7) + fl * 8) = o;
  }
}

// D=64 fp16 in, fp32 out, no relu. 8 lanes x 16B = one row; 8 rows/instr.
// Unroll x2 -> 16 rows in flight. Combine via shfl_xor(8|16|32).
__global__ __launch_bounds__(256) void agg64_h(const half_t* __restrict__ t,
                                               const int* __restrict__ offs,
                                               const int2* __restrict__ edges,
                                               const float* __restrict__ dinv,
                                               const float* __restrict__ bias,
                                               float* __restrict__ out, int n) {
  int gid = blockIdx.x * blockDim.x + threadIdx.x;
  int node = gid >> 6, lane = gid & 63;
  if (node >= n) return;
  int og = lane >> 3;  // eighth id 0..7
  int fl = lane & 7;   // lane in eighth; columns fl*8 .. fl*8+7
  int e0 = offs[node], e1 = offs[node + 1];
  float acc[8] = {0.f, 0.f, 0.f, 0.f, 0.f, 0.f, 0.f, 0.f};
  int e = e0 + og;
  for (; e + 8 < e1; e += 16) {
    int2 da = edges[e], db = edges[e + 8];
    half8_t va = *(const half8_t*)(t + ((size_t)da.x << 6) + fl * 8);
    half8_t vb = *(const half8_t*)(t + ((size_t)db.x << 6) + fl * 8);
    float wa = __int_as_float(da.y), wb = __int_as_float(db.y);
#pragma unroll
    for (int j = 0; j < 8; ++j) {
      acc[j] = fmaf(wa, (float)va[j], acc[j]);
      acc[j] = fmaf(wb, (float)vb[j], acc[j]);
    }
  }
  for (; e < e1; e += 8) {
    int2 d = edges[e];
    half8_t v = *(const half8_t*)(t + ((size_t)d.x << 6) + fl * 8);
    float w = __int_as_float(d.y);
#pragma unroll
    for (int j = 0; j < 8; ++j) acc[j] = fmaf(w, (float)v[j], acc[j]);
  }
#pragma unroll
  for (int j = 0; j < 8; ++j) {
    acc[j] += __shfl_xor(acc[j], 8);
    acc[j] += __shfl_xor(acc[j], 16);
    acc[j] += __shfl_xor(acc[j], 32);
  }
  if (og == 0) {
    float di = dinv[node];
    float dii = di * di;
    half8_t sv = *(const half8_t*)(t + ((size_t)node << 6) + fl * 8);
    float4 b0 = *(const float4*)(bias + fl * 8);
    float4 b1 = *(const float4*)(bias + fl * 8 + 4);
    float bb[8] = {b0.x, b0.y, b0.z, b0.w, b1.x, b1.y, b1.z, b1.w};
    float4 o0, o1;
    float ov[8];
#pragma unroll
    for (int j = 0; j < 8; ++j) ov[j] = di * acc[j] + dii * (float)sv[j] + bb[j];
    o0 = make_float4(ov[0], ov[1], ov[2], ov[3]);
    o1 = make_float4(ov[4], ov[5], ov[6], ov[7]);
    *(float4*)(out + ((size_t)node << 6) + fl * 8) = o0;
    *(float4*)(out + ((size_t)node << 6) + fl * 8 + 4) = o1;
  }
}

extern "C" void kernel_launch(void* const* d_in, const int* in_sizes, int n_in,
                              void* d_out, int out_size, void* d_ws, size_t ws_size,
                              hipStream_t stream) {
  const float* x = (const float*)d_in[0];
  const int* ei = (const int*)d_in[1];
  const float* gamma = (const float*)d_in[2];
  const float* beta = (const float*)d_in[3];
  const float* W1 = (const float*)d_in[4];
  const float* b1 = (const float*)d_in[5];
  const float* W2 = (const float*)d_in[6];
  const float* b2 = (const float*)d_in[7];
  const float* W3 = (const float*)d_in[8];
  const float* b3 = (const float*)d_in[9];
  float* out = (float*)d_out;

  const int N = in_sizes[0] / 256;
  const int E = in_sizes[1] / 2;
  const int* src = ei;
  const int* dst = ei + E;
  const int NB = (N + 255) >> 8;

  char* ws = (char*)d_ws;
  auto alloc = [&](size_t bytes) -> char* {
    char* p = ws;
    ws += (bytes + 255) & ~(size_t)255;
    return p;
  };
  int* bcnt = (int*)alloc(256 * 4);
  int* bbase = (int*)alloc(257 * 4);
  int* bcur = (int*)alloc(256 * 4);
  int2* binned = (int2*)alloc((size_t)E * 8);
  int* srcs = (int*)alloc((size_t)E * 4);
  int* offs = (int*)alloc((size_t)(N + 1) * 4);
  float* dinv = (float*)alloc((size_t)N * 4);
  int2* edges = (int2*)alloc((size_t)E * 8);
  float* mu = (float*)alloc((size_t)N * 4);
  float* rs = (float*)alloc((size_t)N * 4);
  half_t* t = (half_t*)alloc((size_t)N * 128 * 2);
  half_t* h = (half_t*)alloc((size_t)N * 128 * 2);
  unsigned short* W1t_hi = (unsigned short*)alloc(256 * 128 * 2);
  unsigned short* W1t_lo = (unsigned short*)alloc(256 * 128 * 2);
  unsigned short* W2t_hi = (unsigned short*)alloc(128 * 128 * 2);
  unsigned short* W2t_lo = (unsigned short*)alloc(128 * 128 * 2);
  unsigned short* W3t_hi = (unsigned short*)alloc(128 * 64 * 2);
  unsigned short* W3t_lo = (unsigned short*)alloc(128 * 64 * 2);

  // ---- CSR build via 2-level bucket sort ----
  zero_ctl<<<1, 256, 0, stream>>>(bcnt, 256);
  hist_bucket<<<256, 256, 0, stream>>>(dst, bcnt, E, NB);
  scan_buckets<<<1, 256, 0, stream>>>(bcnt, bbase, bcur, NB, E);
  scatter_bins<<<(E + CHUNK - 1) / CHUNK, 256, 0, stream>>>(src, dst, bcur, binned, E);
  sort_bucket<<<NB, 256, 0, stream>>>(binned, bbase, srcs, offs, dinv, N, NB, E);
  fill_w<<<(E + 255) / 256, 256, 0, stream>>>(srcs, dinv, edges, E);

  // ---- weight transpose + bf16 hi/lo split ----
  wsplit<<<(256 * 128 + 255) / 256, 256, 0, stream>>>(W1, W1t_hi, W1t_lo, 256, 128);
  wsplit<<<(128 * 128 + 255) / 256, 256, 0, stream>>>(W2, W2t_hi, W2t_lo, 128, 128);
  wsplit<<<(128 * 64 + 255) / 256, 256, 0, stream>>>(W3, W3t_hi, W3t_lo, 128, 64);

  // ---- layernorm stats ----
  ln_stats<<<(N + 3) / 4, 256, 0, stream>>>(x, mu, rs, N);

  const int gemm_blocks = (N + 63) / 64;
  const int agg_blocks = (N + 3) / 4;

  // ---- layer 1 ----
  gemm_mfma<256, 128, true, false><<<gemm_blocks, 256, 0, stream>>>(
      x, W1t_hi, W1t_lo, mu, rs, gamma, beta, t, N);
  agg128_h<<<agg_blocks, 256, 0, stream>>>(t, offs, edges, dinv, b1, h, N);

  // ---- layer 2 ----
  gemm_mfma<128, 128, false, true><<<gemm_blocks, 256, 0, stream>>>(
      h, W2t_hi, W2t_lo, nullptr, nullptr, nullptr, nullptr, t, N);
  agg128_h<<<agg_blocks, 256, 0, stream>>>(t, offs, edges, dinv, b2, h, N);

  // ---- layer 3 ----
  gemm_mfma<128, 64, false, true><<<gemm_blocks, 256, 0, stream>>>(
      h, W3t_hi, W3t_lo, nullptr, nullptr, nullptr, nullptr, t, N);
  agg64_h<<<agg_blocks, 256, 0, stream>>>(t, offs, edges, dinv, b3, out, N);
}